// Round 1
// 583.194 us; speedup vs baseline: 1.0227x; 1.0227x over previous
//
#include <hip/hip_runtime.h>
#include <hip/hip_bf16.h>
#include <stdint.h>

// SpectralNonLocalBlock on MI355X.
//   M[b]  = x1[b] @ x0[b]^T            (256x256 Gram, K=16384)   -- K1 (split-K 32, hi/lo bf16, cvt_pk)
//   f     = Tw M Pw^T + tb*SP[d] + SA[c]*pb                      -- K2a/K2b1
//   F     = softmax_c(f)                                         -- K2b2 (wave-parallel)
//   G     = F @ g_w ; yb = F @ g_b                               -- K2c
//   x0T   = transpose(x0) bf16, layout [r=n&63][q=n>>6][e]       -- KT (fast path)
//   yvT[nv][cv] = viewT : y tiles from G @ x0T, LDS-free         -- K3a_f
//   out   = W_w @ view + W_b, LDS-free (B = yvT rows)            -- K3b_f
// Fallback (small ws): old LDS-staged k3a/k3b on y2-flat yv.

typedef __attribute__((ext_vector_type(4))) float f32x4;
typedef __attribute__((ext_vector_type(8))) short s16x8;

#define MFMA16(A,B,C) __builtin_amdgcn_mfma_f32_16x16x32_bf16((A),(B),(C),0,0,0)

__device__ __forceinline__ short f2bf(float f) {
    union { float f; uint32_t u; } v; v.f = f;
    uint32_t r = v.u + 0x7fffu + ((v.u >> 16) & 1u);
    return (short)(r >> 16);
}
__device__ __forceinline__ float bf2f(short h) {
    union { uint32_t u; float f; } v; v.u = ((uint32_t)(uint16_t)h) << 16;
    return v.f;
}
// packed RNE f32x2 -> bf16x2 (no builtin on gfx950; inline asm per guide T12)
__device__ __forceinline__ uint32_t cvtpk(float a, float b) {
    uint32_t r;
    asm("v_cvt_pk_bf16_f32 %0, %1, %2" : "=v"(r) : "v"(a), "v"(b));
    return r;
}
__device__ __forceinline__ void pack2_hl(f32x4 a, f32x4 b, s16x8& hi, s16x8& lo) {
    float v[8] = {a.x,a.y,a.z,a.w,b.x,b.y,b.z,b.w};
    uint32_t h[4]; float r[8];
#pragma unroll
    for (int i=0;i<4;++i) {
        h[i] = cvtpk(v[2*i], v[2*i+1]);
        float f0 = __uint_as_float(h[i] << 16);
        float f1 = __uint_as_float(h[i] & 0xffff0000u);
        r[2*i]   = v[2*i]   - f0;
        r[2*i+1] = v[2*i+1] - f1;
    }
    union { uint32_t u[4]; s16x8 s; } H, L;
#pragma unroll
    for (int i=0;i<4;++i) { H.u[i] = h[i]; L.u[i] = cvtpk(r[2*i], r[2*i+1]); }
    hi = H.s; lo = L.s;
}
__device__ __forceinline__ float hsum4(f32x4 v){ return (v.x+v.y)+(v.z+v.w); }

// ---------------- K0: weight prep (g_w transpose->bf16, W_w->bf16, zero s0/s1)
__global__ __launch_bounds__(256) void k0_prep(
    const float* __restrict__ g_w, const float* __restrict__ W_w,
    short* __restrict__ gwT, short* __restrict__ Wwb,
    float* __restrict__ s0, float* __restrict__ s1)
{
    int gid = blockIdx.x * 256 + threadIdx.x;   // 65536
    int d = gid >> 8, e = gid & 255;
    gwT[e*256 + d] = f2bf(g_w[gid]);            // gwT[e][d] = g_w[d][e]
    Wwb[gid] = f2bf(W_w[gid]);
    if (gid < 2048) { s0[gid] = 0.f; s1[gid] = 0.f; }
}

// ---------------- K1: Gram split-K (32 chunks) with hi/lo bf16 (hh+hl+lh MFMAs).
// grid = 8b * 32chunk * 4ij (ij fastest) = 1024 blocks -> 4 blocks/CU (LDS 40KB x4 = 160KB)
__global__ __launch_bounds__(256) void k1_gram(
    const float* __restrict__ x0, const float* __restrict__ x1,
    float* __restrict__ partial, float* __restrict__ s0, float* __restrict__ s1)
{
    __shared__ short Ah[128*40], Al[128*40], Bh[128*40], Bl[128*40];
    int bid = blockIdx.x;
    int ij = bid & 3, ch = (bid >> 2) & 31, b = bid >> 7;
    int i0 = (ij >> 1) * 128, j0 = (ij & 1) * 128, k0 = ch * 512;
    int tid = threadIdx.x;
    int w = tid >> 6, lane = tid & 63;
    int wr = (w >> 1) * 64, wc = (w & 1) * 64;
    int quad = lane >> 4, l16 = lane & 15;
    int srow = tid >> 1, skk = (tid & 1) * 16;

    const float* pa = x1 + (size_t)(b*256 + i0 + srow)*16384 + k0 + skk;
    const float* pb = x0 + (size_t)(b*256 + j0 + srow)*16384 + k0 + skk;

    f32x4 acc[4][4];
#pragma unroll
    for (int i=0;i<4;i++)
#pragma unroll
    for (int j=0;j<4;j++) acc[i][j] = f32x4{0.f,0.f,0.f,0.f};

    float sumA = 0.f, sumB = 0.f;

    for (int s = 0; s < 16; ++s) {
        f32x4 av[4], bv[4];
#pragma unroll
        for (int q=0;q<4;++q) { av[q] = *(const f32x4*)(pa + q*4); bv[q] = *(const f32x4*)(pb + q*4); }
        pa += 32; pb += 32;
#pragma unroll
        for (int q=0;q<4;++q) { sumA += hsum4(av[q]); sumB += hsum4(bv[q]); }
        __syncthreads();
        s16x8 h, l;
        pack2_hl(av[0], av[1], h, l);
        ((s16x8*)(Ah + srow*40 + skk))[0] = h; ((s16x8*)(Al + srow*40 + skk))[0] = l;
        pack2_hl(av[2], av[3], h, l);
        ((s16x8*)(Ah + srow*40 + skk))[1] = h; ((s16x8*)(Al + srow*40 + skk))[1] = l;
        pack2_hl(bv[0], bv[1], h, l);
        ((s16x8*)(Bh + srow*40 + skk))[0] = h; ((s16x8*)(Bl + srow*40 + skk))[0] = l;
        pack2_hl(bv[2], bv[3], h, l);
        ((s16x8*)(Bh + srow*40 + skk))[1] = h; ((s16x8*)(Bl + srow*40 + skk))[1] = l;
        __syncthreads();
        s16x8 ah[4], al[4], bh[4], bl[4];
#pragma unroll
        for (int mt=0; mt<4; ++mt) {
            ah[mt] = *(const s16x8*)(Ah + (wr + mt*16 + l16)*40 + quad*8);
            al[mt] = *(const s16x8*)(Al + (wr + mt*16 + l16)*40 + quad*8);
        }
#pragma unroll
        for (int nt=0; nt<4; ++nt) {
            bh[nt] = *(const s16x8*)(Bh + (wc + nt*16 + l16)*40 + quad*8);
            bl[nt] = *(const s16x8*)(Bl + (wc + nt*16 + l16)*40 + quad*8);
        }
#pragma unroll
        for (int mt=0; mt<4; ++mt)
#pragma unroll
        for (int nt=0; nt<4; ++nt) {
            acc[mt][nt] = MFMA16(ah[mt], bh[nt], acc[mt][nt]);
            acc[mt][nt] = MFMA16(ah[mt], bl[nt], acc[mt][nt]);
            acc[mt][nt] = MFMA16(al[mt], bh[nt], acc[mt][nt]);
        }
    }
    // row sums (each row staged by thread pair (t, t+1))
    float oA = sumA + __shfl_down(sumA, 1);
    float oB = sumB + __shfl_down(sumB, 1);
    if ((tid & 1) == 0) {
        if (j0 == 0) atomicAdd(&s1[b*256 + i0 + srow], oA);
        if (i0 == 0) atomicAdd(&s0[b*256 + j0 + srow], oB);
    }
    float* outp = partial + (size_t)bid * 16384;
#pragma unroll
    for (int mt=0; mt<4; ++mt)
#pragma unroll
    for (int nt=0; nt<4; ++nt)
#pragma unroll
    for (int r=0; r<4; ++r) {
        int row = wr + mt*16 + quad*4 + r;
        int col = wc + nt*16 + l16;
        outp[row*128 + col] = acc[mt][nt][r];
    }
}

// ---------------- K1r: reduce partials -> M
__global__ __launch_bounds__(256) void k1_reduce(
    const float* __restrict__ partial, float* __restrict__ M)
{
    int gid = blockIdx.x*256 + threadIdx.x;     // 524288
    int b = gid >> 16;
    int rem = gid & 65535;
    int i = rem >> 8, j = rem & 255;
    int ij = ((i>>7)<<1) | (j>>7);
    int idx = (i&127)*128 + (j&127);
    float s = 0.f;
#pragma unroll
    for (int ch = 0; ch < 32; ++ch)
        s += partial[(size_t)((b*32 + ch)*4 + ij)*16384 + idx];
    M[gid] = s;
}

// ---------------- KT: x0 -> x0T bf16, layout x0T[b][r*256+q][e] where n = q*64+r
// grid = 8b * 4eb * 256nb = 8192
__global__ __launch_bounds__(256) void kT(
    const float* __restrict__ x0, short* __restrict__ x0T)
{
    __shared__ short sm[64*72];
    int bid = blockIdx.x;
    int b = bid >> 10, eb = (bid >> 8) & 3, nb = bid & 255;
    int e0 = eb*64, n0 = nb*64;
    int t = threadIdx.x;
    int eg = t >> 4, np = (t & 15)*4;
    const float* p0 = x0 + (size_t)(b*256 + e0 + eg*4)*16384 + n0 + np;
    f32x4 r0 = *(const f32x4*)(p0);
    f32x4 r1 = *(const f32x4*)(p0 + 16384);
    f32x4 r2 = *(const f32x4*)(p0 + 32768);
    f32x4 r3 = *(const f32x4*)(p0 + 49152);
    float a0[4] = {r0.x,r0.y,r0.z,r0.w};
    float a1[4] = {r1.x,r1.y,r1.z,r1.w};
    float a2[4] = {r2.x,r2.y,r2.z,r2.w};
    float a3[4] = {r3.x,r3.y,r3.z,r3.w};
#pragma unroll
    for (int j=0;j<4;++j) {
        uint32_t u0 = cvtpk(a0[j], a1[j]);   // e = eg*4+0, +1 (lo=src0)
        uint32_t u1 = cvtpk(a2[j], a3[j]);   // e = eg*4+2, +3
        uint32_t* d = (uint32_t*)(sm + (np+j)*72 + eg*4);
        d[0] = u0; d[1] = u1;
    }
    __syncthreads();
    int nl = t >> 2, ec = (t & 3)*16;       // n-local row, 16-e slice
    s16x8 w0 = *(const s16x8*)(sm + nl*72 + ec);
    s16x8 w1 = *(const s16x8*)(sm + nl*72 + ec + 8);
    // n = n0 + nl -> r = nl (n0 mult of 64), q = nb
    short* dst = x0T + (size_t)b*4194304 + (size_t)(nl*256 + nb)*256 + e0 + ec;
    ((s16x8*)dst)[0] = w0;
    ((s16x8*)dst)[1] = w1;
}

// ---------------- K2m: SA = Tw@s1 ; SP = Pw@s0 + N*pb. grid = 16
__global__ __launch_bounds__(256) void k2m(
    const float* __restrict__ Tw, const float* __restrict__ Pw,
    const float* __restrict__ pb, const float* __restrict__ s0,
    const float* __restrict__ s1, float* __restrict__ SA, float* __restrict__ SP)
{
    __shared__ float sv[256];
    int b = blockIdx.x >> 1, which = blockIdx.x & 1;
    int t = threadIdx.x;
    sv[t] = which ? s0[b*256 + t] : s1[b*256 + t];
    __syncthreads();
    const float* W = which ? Pw : Tw;
    const float* row = W + t*256;
    float acc = 0.f;
    for (int i = 0; i < 256; ++i) acc += row[i] * sv[i];
    if (which) SP[b*256 + t] = acc + 16384.f * pb[t];
    else       SA[b*256 + t] = acc;
}

// ---------------- K2a: P1T[b][d][i] = sum_j Pw[d,j] M[b,i,j]  (hi/lo split)
__global__ __launch_bounds__(256) void k2a(
    const float* __restrict__ Pw, const float* __restrict__ M, float* __restrict__ P1T)
{
    __shared__ short Ah[128*40], Al[128*40], Bh[128*40], Bl[128*40];
    int bid = blockIdx.x;
    int b = bid >> 2, d0 = ((bid>>1)&1)*128, i0 = (bid&1)*128;
    int tid = threadIdx.x;
    int w = tid >> 6, lane = tid & 63;
    int wr = (w >> 1) * 64, wc = (w & 1) * 64;
    int quad = lane >> 4, l16 = lane & 15;
    int srow = tid >> 1, skk = (tid & 1) * 16;

    f32x4 acc[4][4];
#pragma unroll
    for (int i=0;i<4;i++)
#pragma unroll
    for (int j=0;j<4;j++) acc[i][j] = f32x4{0.f,0.f,0.f,0.f};

    for (int s = 0; s < 8; ++s) {
        const float* pa = Pw + (d0 + srow)*256 + s*32 + skk;
        const float* pm = M + (size_t)b*65536 + (i0 + srow)*256 + s*32 + skk;
        f32x4 av[4], bv[4];
#pragma unroll
        for (int q=0;q<4;++q) { av[q] = *(const f32x4*)(pa + q*4); bv[q] = *(const f32x4*)(pm + q*4); }
        __syncthreads();
        s16x8 h, l;
        pack2_hl(av[0], av[1], h, l);
        ((s16x8*)(Ah + srow*40 + skk))[0] = h; ((s16x8*)(Al + srow*40 + skk))[0] = l;
        pack2_hl(av[2], av[3], h, l);
        ((s16x8*)(Ah + srow*40 + skk))[1] = h; ((s16x8*)(Al + srow*40 + skk))[1] = l;
        pack2_hl(bv[0], bv[1], h, l);
        ((s16x8*)(Bh + srow*40 + skk))[0] = h; ((s16x8*)(Bl + srow*40 + skk))[0] = l;
        pack2_hl(bv[2], bv[3], h, l);
        ((s16x8*)(Bh + srow*40 + skk))[1] = h; ((s16x8*)(Bl + srow*40 + skk))[1] = l;
        __syncthreads();
        s16x8 ah[4], al[4], bh[4], bl[4];
#pragma unroll
        for (int mt=0; mt<4; ++mt) {
            ah[mt] = *(const s16x8*)(Ah + (wr + mt*16 + l16)*40 + quad*8);
            al[mt] = *(const s16x8*)(Al + (wr + mt*16 + l16)*40 + quad*8);
        }
#pragma unroll
        for (int nt=0; nt<4; ++nt) {
            bh[nt] = *(const s16x8*)(Bh + (wc + nt*16 + l16)*40 + quad*8);
            bl[nt] = *(const s16x8*)(Bl + (wc + nt*16 + l16)*40 + quad*8);
        }
#pragma unroll
        for (int mt=0; mt<4; ++mt)
#pragma unroll
        for (int nt=0; nt<4; ++nt) {
            acc[mt][nt] = MFMA16(ah[mt], bh[nt], acc[mt][nt]);
            acc[mt][nt] = MFMA16(ah[mt], bl[nt], acc[mt][nt]);
            acc[mt][nt] = MFMA16(al[mt], bh[nt], acc[mt][nt]);
        }
    }
#pragma unroll
    for (int mt=0; mt<4; ++mt)
#pragma unroll
    for (int nt=0; nt<4; ++nt)
#pragma unroll
    for (int r=0; r<4; ++r) {
        int row = wr + mt*16 + quad*4 + r;
        int col = wc + nt*16 + l16;
        P1T[(size_t)b*65536 + (d0+row)*256 + i0 + col] = acc[mt][nt][r];
    }
}

// ---------------- K2b1: f[b][d][c] = sum_i Tw[c,i] P1T[d,i] + biases. tile 256c x 64d
__global__ __launch_bounds__(256) void k2b1(
    const float* __restrict__ Tw, const float* __restrict__ P1T,
    const float* __restrict__ tb, const float* __restrict__ pb,
    const float* __restrict__ SA, const float* __restrict__ SP,
    float* __restrict__ fws)
{
    __shared__ short Ah[256*40], Al[256*40], Bh[64*40], Bl[64*40];
    int bid = blockIdx.x;
    int b = bid >> 2, d0 = (bid & 3)*64;
    int tid = threadIdx.x;
    int w = tid >> 6, lane = tid & 63;
    int quad = lane >> 4, l16 = lane & 15;

    f32x4 acc[4][4];
#pragma unroll
    for (int i=0;i<4;i++)
#pragma unroll
    for (int j=0;j<4;j++) acc[i][j] = f32x4{0.f,0.f,0.f,0.f};

    for (int s = 0; s < 8; ++s) {
        const float* pa = Tw + tid*256 + s*32;
        f32x4 av[8];
#pragma unroll
        for (int q=0;q<8;++q) av[q] = *(const f32x4*)(pa + q*4);
        const float* pbp = P1T + (size_t)b*65536 + (d0 + (tid>>2))*256 + s*32 + (tid&3)*8;
        f32x4 bv0 = *(const f32x4*)(pbp), bv1 = *(const f32x4*)(pbp + 4);
        __syncthreads();
        s16x8 h, l;
#pragma unroll
        for (int q=0;q<4;++q) {
            pack2_hl(av[2*q], av[2*q+1], h, l);
            ((s16x8*)(Ah + tid*40))[q] = h;
            ((s16x8*)(Al + tid*40))[q] = l;
        }
        pack2_hl(bv0, bv1, h, l);
        *(s16x8*)(Bh + (tid>>2)*40 + (tid&3)*8) = h;
        *(s16x8*)(Bl + (tid>>2)*40 + (tid&3)*8) = l;
        __syncthreads();
        s16x8 ah[4], al[4], bh[4], bl[4];
#pragma unroll
        for (int mt=0; mt<4; ++mt) {
            ah[mt] = *(const s16x8*)(Ah + (w*64 + mt*16 + l16)*40 + quad*8);
            al[mt] = *(const s16x8*)(Al + (w*64 + mt*16 + l16)*40 + quad*8);
        }
#pragma unroll
        for (int nt=0; nt<4; ++nt) {
            bh[nt] = *(const s16x8*)(Bh + (nt*16 + l16)*40 + quad*8);
            bl[nt] = *(const s16x8*)(Bl + (nt*16 + l16)*40 + quad*8);
        }
#pragma unroll
        for (int mt=0; mt<4; ++mt)
#pragma unroll
        for (int nt=0; nt<4; ++nt) {
            acc[mt][nt] = MFMA16(ah[mt], bh[nt], acc[mt][nt]);
            acc[mt][nt] = MFMA16(ah[mt], bl[nt], acc[mt][nt]);
            acc[mt][nt] = MFMA16(al[mt], bh[nt], acc[mt][nt]);
        }
    }
#pragma unroll
    for (int mt=0; mt<4; ++mt)
#pragma unroll
    for (int nt=0; nt<4; ++nt)
#pragma unroll
    for (int r=0; r<4; ++r) {
        int c = w*64 + mt*16 + quad*4 + r;
        int d = d0 + nt*16 + l16;
        float fv = acc[mt][nt][r] + tb[c]*SP[b*256 + d] + SA[b*256 + c]*pb[d];
        fws[(size_t)b*65536 + d*256 + c] = fv;
    }
}

// ---------------- K2b2: column softmax (over c) -> F[b][c][d] bf16.
// one wave per d; lanes cover c = lane + {0,64,128,192}. grid = 8b*64
__global__ __launch_bounds__(256) void k2b2(
    const float* __restrict__ fws, short* __restrict__ F)
{
    int b = blockIdx.x >> 6;
    int d = (blockIdx.x & 63)*4 + (threadIdx.x >> 6);
    int lane = threadIdx.x & 63;
    const float* fr = fws + (size_t)b*65536 + d*256;
    float v[4];
#pragma unroll
    for (int i=0;i<4;++i) v[i] = fr[lane + i*64];
    float mx = fmaxf(fmaxf(v[0],v[1]), fmaxf(v[2],v[3]));
#pragma unroll
    for (int off=32; off>0; off>>=1) mx = fmaxf(mx, __shfl_xor(mx, off));
    float s = 0.f;
#pragma unroll
    for (int i=0;i<4;++i) { v[i] = __expf(v[i] - mx); s += v[i]; }
#pragma unroll
    for (int off=32; off>0; off>>=1) s += __shfl_xor(s, off);
    float inv = 1.f / s;
#pragma unroll
    for (int i=0;i<4;++i)
        F[(size_t)b*65536 + (size_t)(lane + i*64)*256 + d] = f2bf(v[i] * inv);
}

// ---------------- K2c: G[b][c][e] = sum_d F[c,d] g_w[d,e] ; yb = F@g_b
__global__ __launch_bounds__(256) void k2c(
    const short* __restrict__ F, const short* __restrict__ gwT,
    const float* __restrict__ g_b, short* __restrict__ G, float* __restrict__ yb)
{
    int bid = blockIdx.x;
    int b = bid >> 2, c0 = ((bid>>1)&1)*128, e0 = (bid&1)*128;
    int tid = threadIdx.x;
    int w = tid >> 6, lane = tid & 63;
    int wr = (w >> 1) * 64, wc = (w & 1) * 64;
    int quad = lane >> 4, l16 = lane & 15;

    f32x4 acc[4][4];
#pragma unroll
    for (int i=0;i<4;i++)
#pragma unroll
    for (int j=0;j<4;j++) acc[i][j] = f32x4{0.f,0.f,0.f,0.f};

    for (int s = 0; s < 8; ++s) {
        int k0 = s*32;
        s16x8 af[4], bfr[4];
#pragma unroll
        for (int mt=0; mt<4; ++mt)
            af[mt] = *(const s16x8*)(F + (size_t)b*65536 + (c0 + wr + mt*16 + l16)*256 + k0 + quad*8);
#pragma unroll
        for (int nt=0; nt<4; ++nt)
            bfr[nt] = *(const s16x8*)(gwT + (e0 + wc + nt*16 + l16)*256 + k0 + quad*8);
#pragma unroll
        for (int mt=0; mt<4; ++mt)
#pragma unroll
        for (int nt=0; nt<4; ++nt)
            acc[mt][nt] = MFMA16(af[mt], bfr[nt], acc[mt][nt]);
    }
#pragma unroll
    for (int mt=0; mt<4; ++mt)
#pragma unroll
    for (int nt=0; nt<4; ++nt)
#pragma unroll
    for (int r=0; r<4; ++r) {
        int c = c0 + wr + mt*16 + quad*4 + r;
        int e = e0 + wc + nt*16 + l16;
        G[(size_t)b*65536 + c*256 + e] = f2bf(acc[mt][nt][r]);
    }
    if (e0 == 0 && tid < 128) {
        int c = c0 + tid;
        float a = 0.f;
        const short* fr = F + (size_t)b*65536 + c*256;
        for (int d=0; d<256; ++d) a += bf2f(fr[d]) * g_b[d];
        yb[b*256 + c] = a;
    }
}

// ---------------- K3a_f: y in transposed-view layout, LDS-free direct-load MFMA.
// yvT[b][r*256+c][q] = sum_e G[c][e] * x0T[r*256+q][e] + yb[c]
// grid = 8b * 64r * 2c0 * 2q0 = 2048
__global__ __launch_bounds__(256) void k3a_f(
    const short* __restrict__ x0T, const short* __restrict__ G,
    const float* __restrict__ yb, short* __restrict__ yvT)
{
    int bid = blockIdx.x;
    int b = bid >> 8, r = (bid >> 2) & 63, c0 = ((bid>>1)&1)*128, q0 = (bid&1)*128;
    int tid = threadIdx.x;
    int w = tid >> 6, lane = tid & 63;
    int wr = (w >> 1) * 64, wc = (w & 1) * 64;
    int quad = lane >> 4, l16 = lane & 15;

    const short* Gb = G + (size_t)b*65536;
    const short* Xb = x0T + (size_t)b*4194304 + (size_t)r*65536;

    f32x4 acc[4][4];
#pragma unroll
    for (int i=0;i<4;i++)
#pragma unroll
    for (int j=0;j<4;j++) acc[i][j] = f32x4{0.f,0.f,0.f,0.f};

    for (int s = 0; s < 8; ++s) {
        int k0 = s*32;
        s16x8 af[4], bfr[4];
#pragma unroll
        for (int mt=0; mt<4; ++mt)
            af[mt] = *(const s16x8*)(Gb + (c0 + wr + mt*16 + l16)*256 + k0 + quad*8);
#pragma unroll
        for (int nt=0; nt<4; ++nt)
            bfr[nt] = *(const s16x8*)(Xb + (q0 + wc + nt*16 + l16)*256 + k0 + quad*8);
#pragma unroll
        for (int mt=0; mt<4; ++mt)
#pragma unroll
        for (int nt=0; nt<4; ++nt)
            acc[mt][nt] = MFMA16(af[mt], bfr[nt], acc[mt][nt]);
    }
    short* dst = yvT + (size_t)b*4194304 + (size_t)r*65536;
#pragma unroll
    for (int mt=0; mt<4; ++mt)
#pragma unroll
    for (int nt=0; nt<4; ++nt)
#pragma unroll
    for (int rr=0; rr<4; ++rr) {
        int c = c0 + wr + mt*16 + quad*4 + rr;
        int q = q0 + wc + nt*16 + l16;
        dst[(size_t)c*256 + q] = f2bf(acc[mt][nt][rr] + yb[b*256 + c]);
    }
}

// ---------------- K3b_f: out = W_w @ view + W_b, B-operand = yvT rows (LDS-free).
// grid = 8b * 2o * 128n = 2048
__global__ __launch_bounds__(256) void k3b_f(
    const short* __restrict__ yvT, const short* __restrict__ Wwb,
    const float* __restrict__ W_b, float* __restrict__ out)
{
    int bid = blockIdx.x;
    int b = bid >> 8, rem = bid & 255;
    int o0 = (rem >> 7) * 128, n0 = (rem & 127) * 128;
    int tid = threadIdx.x;
    int w = tid >> 6, lane = tid & 63;
    int wr = (w >> 1) * 64, wc = (w & 1) * 64;
    int quad = lane >> 4, l16 = lane & 15;

    const short* Yb = yvT + (size_t)b*4194304;

    f32x4 acc[4][4];
#pragma unroll
    for (int i=0;i<4;i++)
#pragma unroll
    for (int j=0;j<4;j++) acc[i][j] = f32x4{0.f,0.f,0.f,0.f};

    for (int s = 0; s < 8; ++s) {
        int k0 = s*32;
        s16x8 af[4], bfr[4];
#pragma unroll
        for (int mt=0; mt<4; ++mt)
            af[mt] = *(const s16x8*)(Wwb + (o0 + wr + mt*16 + l16)*256 + k0 + quad*8);
#pragma unroll
        for (int nt=0; nt<4; ++nt)
            bfr[nt] = *(const s16x8*)(Yb + (size_t)(n0 + wc + nt*16 + l16)*256 + k0 + quad*8);
#pragma unroll
        for (int mt=0; mt<4; ++mt)
#pragma unroll
        for (int nt=0; nt<4; ++nt)
            acc[mt][nt] = MFMA16(af[mt], bfr[nt], acc[mt][nt]);
    }
#pragma unroll
    for (int mt=0; mt<4; ++mt)
#pragma unroll
    for (int nt=0; nt<4; ++nt)
#pragma unroll
    for (int r=0; r<4; ++r) {
        int o  = o0 + wr + mt*16 + quad*4 + r;
        int nn = n0 + wc + nt*16 + l16;
        out[(size_t)(b*256 + o)*16384 + nn] = acc[mt][nt][r] + W_b[o];
    }
}

// ---------------- Fallback (small ws): old K3a/K3b (LDS-staged, y2-flat yv)
__global__ __launch_bounds__(256) void k3a(
    const float* __restrict__ x0, const short* __restrict__ G,
    const float* __restrict__ yb, short* __restrict__ yv)
{
    __shared__ short smX[64*40];
    int bid = blockIdx.x;
    int b = bid >> 8, m0 = (bid & 255) * 64;
    int tid = threadIdx.x;
    int w = tid >> 6, lane = tid & 63;
    int quad = lane >> 4, l16 = lane & 15;
    int rc = w * 64;
    int se = tid >> 3, sm = (tid & 7) * 8;

    const float* px = x0 + (size_t)(b*256 + se)*16384 + m0 + sm;

    f32x4 acc[4][4];
#pragma unroll
    for (int i=0;i<4;i++)
#pragma unroll
    for (int j=0;j<4;j++) acc[i][j] = f32x4{0.f,0.f,0.f,0.f};

    for (int s = 0; s < 8; ++s) {
        int e0 = s*32;
        f32x4 v0 = *(const f32x4*)(px);
        f32x4 v1 = *(const f32x4*)(px + 4);
        px += (size_t)32*16384;
        __syncthreads();
        short hv[8] = {f2bf(v0.x),f2bf(v0.y),f2bf(v0.z),f2bf(v0.w),
                       f2bf(v1.x),f2bf(v1.y),f2bf(v1.z),f2bf(v1.w)};
#pragma unroll
        for (int i=0;i<8;++i) smX[(sm + i)*40 + se] = hv[i];
        __syncthreads();
        s16x8 af[4], bfr[4];
#pragma unroll
        for (int mt=0; mt<4; ++mt)
            af[mt] = *(const s16x8*)(smX + (mt*16 + l16)*40 + quad*8);
#pragma unroll
        for (int nt=0; nt<4; ++nt)
            bfr[nt] = *(const s16x8*)(G + (size_t)b*65536 + (rc + nt*16 + l16)*256 + e0 + quad*8);
#pragma unroll
        for (int mt=0; mt<4; ++mt)
#pragma unroll
        for (int nt=0; nt<4; ++nt)
            acc[mt][nt] = MFMA16(af[mt], bfr[nt], acc[mt][nt]);
    }
    float ybv[4];
#pragma unroll
    for (int nt=0; nt<4; ++nt) ybv[nt] = yb[b*256 + rc + nt*16 + l16];
    short* base = yv + (size_t)b*4194304 + (size_t)m0*256;
#pragma unroll
    for (int mt=0; mt<4; ++mt)
#pragma unroll
    for (int nt=0; nt<4; ++nt)
#pragma unroll
    for (int r=0; r<4; ++r) {
        int m  = mt*16 + quad*4 + r;
        int rr = rc + nt*16 + l16;
        base[m*256 + rr] = f2bf(acc[mt][nt][r] + ybv[nt]);
    }
}

__global__ __launch_bounds__(256) void k3b(
    const short* __restrict__ yv, const short* __restrict__ Wwb,
    const float* __restrict__ W_b, float* __restrict__ out)
{
    __shared__ short smY[128*40];
    int bid = blockIdx.x;
    int b = bid >> 8, rem = bid & 255;
    int o0 = (rem >> 7) * 128, n0 = (rem & 127) * 128;
    int tid = threadIdx.x;
    int w = tid >> 6, lane = tid & 63;
    int wr = (w >> 1) * 64, wc = (w & 1) * 64;
    int quad = lane >> 4, l16 = lane & 15;
    int sc = tid >> 3, sn = (tid & 7) * 16;

    const short* py = yv + (size_t)b*4194304 + (size_t)sc*16384 + n0 + sn;

    f32x4 acc[4][4];
#pragma unroll
    for (int i=0;i<4;i++)
#pragma unroll
    for (int j=0;j<4;j++) acc[i][j] = f32x4{0.f,0.f,0.f,0.f};

    for (int s = 0; s < 8; ++s) {
        int c0 = s*32;
        s16x8 y0 = *(const s16x8*)(py);
        s16x8 y1 = *(const s16x8*)(py + 8);
        py += (size_t)32*16384;
        __syncthreads();
#pragma unroll
        for (int i=0;i<8;++i) { smY[(sn + i)*40 + sc] = y0[i]; smY[(sn + 8 + i)*40 + sc] = y1[i]; }
        __syncthreads();
        s16x8 af[4], bfr[4];
#pragma unroll
        for (int mt=0; mt<4; ++mt)
            af[mt] = *(const s16x8*)(Wwb + (o0 + wr + mt*16 + l16)*256 + c0 + quad*8);
#pragma unroll
        for (int nt=0; nt<4; ++nt)
            bfr[nt] = *(const s16x8*)(smY + (wc + nt*16 + l16)*40 + quad*8);
#pragma unroll
        for (int mt=0; mt<4; ++mt)
#pragma unroll
        for (int nt=0; nt<4; ++nt)
            acc[mt][nt] = MFMA16(af[mt], bfr[nt], acc[mt][nt]);
    }
#pragma unroll
    for (int mt=0; mt<4; ++mt)
#pragma unroll
    for (int nt=0; nt<4; ++nt)
#pragma unroll
    for (int r=0; r<4; ++r) {
        int o  = o0 + wr + mt*16 + quad*4 + r;
        int nn = n0 + wc + nt*16 + l16;
        out[(size_t)(b*256 + o)*16384 + nn] = acc[mt][nt][r] + W_b[o];
    }
}

extern "C" void kernel_launch(void* const* d_in, const int* in_sizes, int n_in,
                              void* d_out, int out_size, void* d_ws, size_t ws_size,
                              hipStream_t stream)
{
    (void)in_sizes; (void)n_in; (void)out_size;
    const float* x0   = (const float*)d_in[0];
    const float* x1   = (const float*)d_in[1];
    const float* g_w  = (const float*)d_in[2];
    const float* g_b  = (const float*)d_in[3];
    const float* th_w = (const float*)d_in[4];
    const float* th_b = (const float*)d_in[5];
    const float* ph_w = (const float*)d_in[6];
    const float* ph_b = (const float*)d_in[7];
    const float* W_w  = (const float*)d_in[8];
    const float* W_b  = (const float*)d_in[9];
    float* out = (float*)d_out;

    char* ws = (char*)d_ws;
    short* yv      = (short*)(ws + 0);          // 67108864 B (aliases partial; dead->live handoff)
    float* partial = (float*)(ws + 0);          // 67108864 B (32 chunks), dead after k1_reduce
    float* M       = (float*)(ws + 67108864);   // 2 MB
    float* P1T     = (float*)(ws + 69206016);   // 2 MB
    float* fws     = (float*)(ws + 71303168);   // 2 MB
    short* F       = (short*)(ws + 73400320);   // 1 MB
    short* G       = (short*)(ws + 74448896);   // 1 MB
    short* gwT     = (short*)(ws + 75497472);   // 128 KB
    short* Wwb     = (short*)(ws + 75628544);   // 128 KB
    float* s0      = (float*)(ws + 75759616);
    float* s1      = (float*)(ws + 75767808);
    float* SA      = (float*)(ws + 75776000);
    float* SP      = (float*)(ws + 75784192);
    float* yb      = (float*)(ws + 75792384);
    short* x0T     = (short*)(ws + 75800576);   // 64 MB (fast path only)
    const size_t WS_NEED_FAST = 75800576u + 67108864u;  // 142909440

    bool fast = (ws_size >= WS_NEED_FAST);

    k0_prep  <<<dim3(256),  dim3(256), 0, stream>>>(g_w, W_w, gwT, Wwb, s0, s1);
    k1_gram  <<<dim3(1024), dim3(256), 0, stream>>>(x0, x1, partial, s0, s1);
    k1_reduce<<<dim3(2048), dim3(256), 0, stream>>>(partial, M);
    if (fast)
        kT   <<<dim3(8192), dim3(256), 0, stream>>>(x0, x0T);
    k2m      <<<dim3(16),   dim3(256), 0, stream>>>(th_w, ph_w, ph_b, s0, s1, SA, SP);
    k2a      <<<dim3(32),   dim3(256), 0, stream>>>(ph_w, M, P1T);
    k2b1     <<<dim3(32),   dim3(256), 0, stream>>>(th_w, P1T, th_b, ph_b, SA, SP, fws);
    k2b2     <<<dim3(512),  dim3(256), 0, stream>>>(fws, F);
    k2c      <<<dim3(32),   dim3(256), 0, stream>>>(F, gwT, g_b, G, yb);
    if (fast) {
        k3a_f<<<dim3(2048), dim3(256), 0, stream>>>(x0T, G, yb, yv);
        k3b_f<<<dim3(2048), dim3(256), 0, stream>>>(yv, Wwb, W_b, out);
    } else {
        k3a  <<<dim3(2048), dim3(256), 0, stream>>>(x0, G, yb, yv);
        k3b  <<<dim3(2048), dim3(256), 0, stream>>>(yv, Wwb, W_b, out);
    }
}

// Round 2
// 532.780 us; speedup vs baseline: 1.1195x; 1.0946x over previous
//
#include <hip/hip_runtime.h>
#include <hip/hip_bf16.h>
#include <stdint.h>

// SpectralNonLocalBlock on MI355X.
//   M[b]  = x1[b] @ x0[b]^T            (256x256 Gram, K=16384)   -- K1 (split-K 32, hi/lo bf16, pipelined)
//   f     = Tw M Pw^T + tb*SP[d] + SA[c]*pb ; SA=Tw@s1, SP=Pw@s0+N*pb   -- K2a/K2b1 (pipelined)
//   F     = softmax_c(f)                                         -- K2b2 (wave-parallel)
//   G     = F @ g_w ; yb = F @ g_b                               -- K2c
//   y     = G @ x0 + yb  (LDS transpose of x0, swizzled dword staging, pipelined) -- K3a
//   out   = W_w @ y_view + W_b (LDS transpose of yv, swizzled, pipelined)         -- K3b
// All MFMA = v_mfma_f32_16x16x32_bf16, gemm_bt style (both operands [row][K]).

typedef __attribute__((ext_vector_type(4))) float f32x4;
typedef __attribute__((ext_vector_type(8))) short s16x8;

#define MFMA16(A,B,C) __builtin_amdgcn_mfma_f32_16x16x32_bf16((A),(B),(C),0,0,0)

__device__ __forceinline__ short f2bf(float f) {
    union { float f; uint32_t u; } v; v.f = f;
    uint32_t r = v.u + 0x7fffu + ((v.u >> 16) & 1u);
    return (short)(r >> 16);
}
__device__ __forceinline__ float bf2f(short h) {
    union { uint32_t u; float f; } v; v.u = ((uint32_t)(uint16_t)h) << 16;
    return v.f;
}
// packed RNE f32x2 -> bf16x2 (lo half = src0)
__device__ __forceinline__ uint32_t cvtpk(float a, float b) {
    uint32_t r;
    asm("v_cvt_pk_bf16_f32 %0, %1, %2" : "=v"(r) : "v"(a), "v"(b));
    return r;
}
__device__ __forceinline__ void pack2_hl(f32x4 a, f32x4 b, s16x8& hi, s16x8& lo) {
    float v[8] = {a.x,a.y,a.z,a.w,b.x,b.y,b.z,b.w};
    uint32_t h[4]; float r[8];
#pragma unroll
    for (int i=0;i<4;++i) {
        h[i] = cvtpk(v[2*i], v[2*i+1]);
        float f0 = __uint_as_float(h[i] << 16);
        float f1 = __uint_as_float(h[i] & 0xffff0000u);
        r[2*i]   = v[2*i]   - f0;
        r[2*i+1] = v[2*i+1] - f1;
    }
    union { uint32_t u[4]; s16x8 s; } H, L;
#pragma unroll
    for (int i=0;i<4;++i) { H.u[i] = h[i]; L.u[i] = cvtpk(r[2*i], r[2*i+1]); }
    hi = H.s; lo = L.s;
}
__device__ __forceinline__ float hsum4(f32x4 v){ return (v.x+v.y)+(v.z+v.w); }

// ---------------- K0: weight prep (g_w transpose->bf16, W_w->bf16, zero s0/s1)
__global__ __launch_bounds__(256) void k0_prep(
    const float* __restrict__ g_w, const float* __restrict__ W_w,
    short* __restrict__ gwT, short* __restrict__ Wwb,
    float* __restrict__ s0, float* __restrict__ s1)
{
    int gid = blockIdx.x * 256 + threadIdx.x;   // 65536
    int d = gid >> 8, e = gid & 255;
    gwT[e*256 + d] = f2bf(g_w[gid]);            // gwT[e][d] = g_w[d][e]
    Wwb[gid] = f2bf(W_w[gid]);
    if (gid < 2048) { s0[gid] = 0.f; s1[gid] = 0.f; }
}

// ---------------- K1: Gram split-K (32 chunks), hi/lo bf16, software-pipelined.
// grid = 8b * 32chunk * 4ij (ij fastest) = 1024 blocks
__global__ __launch_bounds__(256) void k1_gram(
    const float* __restrict__ x0, const float* __restrict__ x1,
    float* __restrict__ partial, float* __restrict__ s0, float* __restrict__ s1)
{
    __shared__ short Ah[128*40], Al[128*40], Bh[128*40], Bl[128*40];
    int bid = blockIdx.x;
    int ij = bid & 3, ch = (bid >> 2) & 31, b = bid >> 7;
    int i0 = (ij >> 1) * 128, j0 = (ij & 1) * 128, k0 = ch * 512;
    int tid = threadIdx.x;
    int w = tid >> 6, lane = tid & 63;
    int wr = (w >> 1) * 64, wc = (w & 1) * 64;
    int quad = lane >> 4, l16 = lane & 15;
    int srow = tid >> 1, skk = (tid & 1) * 16;

    const float* pa = x1 + (size_t)(b*256 + i0 + srow)*16384 + k0 + skk;
    const float* pb = x0 + (size_t)(b*256 + j0 + srow)*16384 + k0 + skk;

    f32x4 acc[4][4];
#pragma unroll
    for (int i=0;i<4;i++)
#pragma unroll
    for (int j=0;j<4;j++) acc[i][j] = f32x4{0.f,0.f,0.f,0.f};

    float sumA = 0.f, sumB = 0.f;

    // preload s=0
    f32x4 av[4], bv[4];
#pragma unroll
    for (int q=0;q<4;++q) { av[q] = *(const f32x4*)(pa + q*4); bv[q] = *(const f32x4*)(pb + q*4); }
    pa += 32; pb += 32;

    for (int s = 0; s < 16; ++s) {
        __syncthreads();                       // LDS free (prev readers done)
#pragma unroll
        for (int q=0;q<4;++q) { sumA += hsum4(av[q]); sumB += hsum4(bv[q]); }
        s16x8 h, l;
        pack2_hl(av[0], av[1], h, l);
        ((s16x8*)(Ah + srow*40 + skk))[0] = h; ((s16x8*)(Al + srow*40 + skk))[0] = l;
        pack2_hl(av[2], av[3], h, l);
        ((s16x8*)(Ah + srow*40 + skk))[1] = h; ((s16x8*)(Al + srow*40 + skk))[1] = l;
        pack2_hl(bv[0], bv[1], h, l);
        ((s16x8*)(Bh + srow*40 + skk))[0] = h; ((s16x8*)(Bl + srow*40 + skk))[0] = l;
        pack2_hl(bv[2], bv[3], h, l);
        ((s16x8*)(Bh + srow*40 + skk))[1] = h; ((s16x8*)(Bl + srow*40 + skk))[1] = l;
        __syncthreads();                       // LDS ready
        f32x4 nav[4], nbv[4];
        if (s < 15) {                          // prefetch s+1 into MFMA shadow
#pragma unroll
            for (int q=0;q<4;++q) { nav[q] = *(const f32x4*)(pa + q*4); nbv[q] = *(const f32x4*)(pb + q*4); }
            pa += 32; pb += 32;
        }
        s16x8 ah[4], al[4], bh[4], bl[4];
#pragma unroll
        for (int mt=0; mt<4; ++mt) {
            ah[mt] = *(const s16x8*)(Ah + (wr + mt*16 + l16)*40 + quad*8);
            al[mt] = *(const s16x8*)(Al + (wr + mt*16 + l16)*40 + quad*8);
        }
#pragma unroll
        for (int nt=0; nt<4; ++nt) {
            bh[nt] = *(const s16x8*)(Bh + (wc + nt*16 + l16)*40 + quad*8);
            bl[nt] = *(const s16x8*)(Bl + (wc + nt*16 + l16)*40 + quad*8);
        }
#pragma unroll
        for (int mt=0; mt<4; ++mt)
#pragma unroll
        for (int nt=0; nt<4; ++nt) {
            acc[mt][nt] = MFMA16(ah[mt], bh[nt], acc[mt][nt]);
            acc[mt][nt] = MFMA16(ah[mt], bl[nt], acc[mt][nt]);
            acc[mt][nt] = MFMA16(al[mt], bh[nt], acc[mt][nt]);
        }
        if (s < 15) {
#pragma unroll
            for (int q=0;q<4;++q) { av[q] = nav[q]; bv[q] = nbv[q]; }
        }
    }
    // row sums (each row staged by thread pair (t, t+1))
    float oA = sumA + __shfl_down(sumA, 1);
    float oB = sumB + __shfl_down(sumB, 1);
    if ((tid & 1) == 0) {
        if (j0 == 0) atomicAdd(&s1[b*256 + i0 + srow], oA);
        if (i0 == 0) atomicAdd(&s0[b*256 + j0 + srow], oB);
    }
    float* outp = partial + (size_t)bid * 16384;
#pragma unroll
    for (int mt=0; mt<4; ++mt)
#pragma unroll
    for (int nt=0; nt<4; ++nt)
#pragma unroll
    for (int r=0; r<4; ++r) {
        int row = wr + mt*16 + quad*4 + r;
        int col = wc + nt*16 + l16;
        outp[row*128 + col] = acc[mt][nt][r];
    }
}

// ---------------- K1r: reduce partials -> M
__global__ __launch_bounds__(256) void k1_reduce(
    const float* __restrict__ partial, float* __restrict__ M)
{
    int gid = blockIdx.x*256 + threadIdx.x;     // 524288
    int b = gid >> 16;
    int rem = gid & 65535;
    int i = rem >> 8, j = rem & 255;
    int ij = ((i>>7)<<1) | (j>>7);
    int idx = (i&127)*128 + (j&127);
    float s = 0.f;
#pragma unroll
    for (int ch = 0; ch < 32; ++ch)
        s += partial[(size_t)((b*32 + ch)*4 + ij)*16384 + idx];
    M[gid] = s;
}

// ---------------- K2m: SA = Tw@s1 ; SP = Pw@s0 + N*pb. grid = 16
__global__ __launch_bounds__(256) void k2m(
    const float* __restrict__ Tw, const float* __restrict__ Pw,
    const float* __restrict__ pb, const float* __restrict__ s0,
    const float* __restrict__ s1, float* __restrict__ SA, float* __restrict__ SP)
{
    __shared__ float sv[256];
    int b = blockIdx.x >> 1, which = blockIdx.x & 1;
    int t = threadIdx.x;
    sv[t] = which ? s0[b*256 + t] : s1[b*256 + t];
    __syncthreads();
    const float* W = which ? Pw : Tw;
    const float* row = W + t*256;
    float acc = 0.f;
    for (int i = 0; i < 256; ++i) acc += row[i] * sv[i];
    if (which) SP[b*256 + t] = acc + 16384.f * pb[t];
    else       SA[b*256 + t] = acc;
}

// ---------------- K2a: P1T[b][d][i] = sum_j Pw[d,j] M[b,i,j]  (hi/lo, pipelined)
__global__ __launch_bounds__(256) void k2a(
    const float* __restrict__ Pw, const float* __restrict__ M, float* __restrict__ P1T)
{
    __shared__ short Ah[128*40], Al[128*40], Bh[128*40], Bl[128*40];
    int bid = blockIdx.x;
    int b = bid >> 2, d0 = ((bid>>1)&1)*128, i0 = (bid&1)*128;
    int tid = threadIdx.x;
    int w = tid >> 6, lane = tid & 63;
    int wr = (w >> 1) * 64, wc = (w & 1) * 64;
    int quad = lane >> 4, l16 = lane & 15;
    int srow = tid >> 1, skk = (tid & 1) * 16;

    f32x4 acc[4][4];
#pragma unroll
    for (int i=0;i<4;i++)
#pragma unroll
    for (int j=0;j<4;j++) acc[i][j] = f32x4{0.f,0.f,0.f,0.f};

    const float* pa0 = Pw + (d0 + srow)*256 + skk;
    const float* pm0 = M + (size_t)b*65536 + (i0 + srow)*256 + skk;

    f32x4 av[4], bv[4];
#pragma unroll
    for (int q=0;q<4;++q) { av[q] = *(const f32x4*)(pa0 + q*4); bv[q] = *(const f32x4*)(pm0 + q*4); }

    for (int s = 0; s < 8; ++s) {
        __syncthreads();
        s16x8 h, l;
        pack2_hl(av[0], av[1], h, l);
        ((s16x8*)(Ah + srow*40 + skk))[0] = h; ((s16x8*)(Al + srow*40 + skk))[0] = l;
        pack2_hl(av[2], av[3], h, l);
        ((s16x8*)(Ah + srow*40 + skk))[1] = h; ((s16x8*)(Al + srow*40 + skk))[1] = l;
        pack2_hl(bv[0], bv[1], h, l);
        ((s16x8*)(Bh + srow*40 + skk))[0] = h; ((s16x8*)(Bl + srow*40 + skk))[0] = l;
        pack2_hl(bv[2], bv[3], h, l);
        ((s16x8*)(Bh + srow*40 + skk))[1] = h; ((s16x8*)(Bl + srow*40 + skk))[1] = l;
        __syncthreads();
        f32x4 nav[4], nbv[4];
        if (s < 7) {
            const float* pa = pa0 + (s+1)*32;
            const float* pm = pm0 + (s+1)*32;
#pragma unroll
            for (int q=0;q<4;++q) { nav[q] = *(const f32x4*)(pa + q*4); nbv[q] = *(const f32x4*)(pm + q*4); }
        }
        s16x8 ah[4], al[4], bh[4], bl[4];
#pragma unroll
        for (int mt=0; mt<4; ++mt) {
            ah[mt] = *(const s16x8*)(Ah + (wr + mt*16 + l16)*40 + quad*8);
            al[mt] = *(const s16x8*)(Al + (wr + mt*16 + l16)*40 + quad*8);
        }
#pragma unroll
        for (int nt=0; nt<4; ++nt) {
            bh[nt] = *(const s16x8*)(Bh + (wc + nt*16 + l16)*40 + quad*8);
            bl[nt] = *(const s16x8*)(Bl + (wc + nt*16 + l16)*40 + quad*8);
        }
#pragma unroll
        for (int mt=0; mt<4; ++mt)
#pragma unroll
        for (int nt=0; nt<4; ++nt) {
            acc[mt][nt] = MFMA16(ah[mt], bh[nt], acc[mt][nt]);
            acc[mt][nt] = MFMA16(ah[mt], bl[nt], acc[mt][nt]);
            acc[mt][nt] = MFMA16(al[mt], bh[nt], acc[mt][nt]);
        }
        if (s < 7) {
#pragma unroll
            for (int q=0;q<4;++q) { av[q] = nav[q]; bv[q] = nbv[q]; }
        }
    }
#pragma unroll
    for (int mt=0; mt<4; ++mt)
#pragma unroll
    for (int nt=0; nt<4; ++nt)
#pragma unroll
    for (int r=0; r<4; ++r) {
        int row = wr + mt*16 + quad*4 + r;
        int col = wc + nt*16 + l16;
        P1T[(size_t)b*65536 + (d0+row)*256 + i0 + col] = acc[mt][nt][r];
    }
}

// ---------------- K2b1: f[b][d][c] = sum_i Tw[c,i] P1T[d,i] + biases. tile 256c x 64d
__global__ __launch_bounds__(256) void k2b1(
    const float* __restrict__ Tw, const float* __restrict__ P1T,
    const float* __restrict__ tb, const float* __restrict__ pb,
    const float* __restrict__ SA, const float* __restrict__ SP,
    float* __restrict__ fws)
{
    __shared__ short Ah[256*40], Al[256*40], Bh[64*40], Bl[64*40];
    int bid = blockIdx.x;
    int b = bid >> 2, d0 = (bid & 3)*64;
    int tid = threadIdx.x;
    int w = tid >> 6, lane = tid & 63;
    int quad = lane >> 4, l16 = lane & 15;

    f32x4 acc[4][4];
#pragma unroll
    for (int i=0;i<4;i++)
#pragma unroll
    for (int j=0;j<4;j++) acc[i][j] = f32x4{0.f,0.f,0.f,0.f};

    const float* pa0 = Tw + tid*256;
    const float* pb0 = P1T + (size_t)b*65536 + (d0 + (tid>>2))*256 + (tid&3)*8;

    f32x4 av[8]; f32x4 bv0, bv1;
#pragma unroll
    for (int q=0;q<8;++q) av[q] = *(const f32x4*)(pa0 + q*4);
    bv0 = *(const f32x4*)(pb0); bv1 = *(const f32x4*)(pb0 + 4);

    for (int s = 0; s < 8; ++s) {
        __syncthreads();
        s16x8 h, l;
#pragma unroll
        for (int q=0;q<4;++q) {
            pack2_hl(av[2*q], av[2*q+1], h, l);
            ((s16x8*)(Ah + tid*40))[q] = h;
            ((s16x8*)(Al + tid*40))[q] = l;
        }
        pack2_hl(bv0, bv1, h, l);
        *(s16x8*)(Bh + (tid>>2)*40 + (tid&3)*8) = h;
        *(s16x8*)(Bl + (tid>>2)*40 + (tid&3)*8) = l;
        __syncthreads();
        f32x4 nav[8], nbv0, nbv1;
        if (s < 7) {
            const float* pa = pa0 + (s+1)*32;
            const float* pbp = pb0 + (s+1)*32;
#pragma unroll
            for (int q=0;q<8;++q) nav[q] = *(const f32x4*)(pa + q*4);
            nbv0 = *(const f32x4*)(pbp); nbv1 = *(const f32x4*)(pbp + 4);
        }
        s16x8 ah[4], al[4], bh[4], bl[4];
#pragma unroll
        for (int mt=0; mt<4; ++mt) {
            ah[mt] = *(const s16x8*)(Ah + (w*64 + mt*16 + l16)*40 + quad*8);
            al[mt] = *(const s16x8*)(Al + (w*64 + mt*16 + l16)*40 + quad*8);
        }
#pragma unroll
        for (int nt=0; nt<4; ++nt) {
            bh[nt] = *(const s16x8*)(Bh + (nt*16 + l16)*40 + quad*8);
            bl[nt] = *(const s16x8*)(Bl + (nt*16 + l16)*40 + quad*8);
        }
#pragma unroll
        for (int mt=0; mt<4; ++mt)
#pragma unroll
        for (int nt=0; nt<4; ++nt) {
            acc[mt][nt] = MFMA16(ah[mt], bh[nt], acc[mt][nt]);
            acc[mt][nt] = MFMA16(ah[mt], bl[nt], acc[mt][nt]);
            acc[mt][nt] = MFMA16(al[mt], bh[nt], acc[mt][nt]);
        }
        if (s < 7) {
#pragma unroll
            for (int q=0;q<8;++q) av[q] = nav[q];
            bv0 = nbv0; bv1 = nbv1;
        }
    }
#pragma unroll
    for (int mt=0; mt<4; ++mt)
#pragma unroll
    for (int nt=0; nt<4; ++nt)
#pragma unroll
    for (int r=0; r<4; ++r) {
        int c = w*64 + mt*16 + quad*4 + r;
        int d = d0 + nt*16 + l16;
        float fv = acc[mt][nt][r] + tb[c]*SP[b*256 + d] + SA[b*256 + c]*pb[d];
        fws[(size_t)b*65536 + d*256 + c] = fv;
    }
}

// ---------------- K2b2: column softmax (over c) -> F[b][c][d] bf16.
// one wave per d; lanes cover c = lane + {0,64,128,192}. grid = 8b*64
__global__ __launch_bounds__(256) void k2b2(
    const float* __restrict__ fws, short* __restrict__ F)
{
    int b = blockIdx.x >> 6;
    int d = (blockIdx.x & 63)*4 + (threadIdx.x >> 6);
    int lane = threadIdx.x & 63;
    const float* fr = fws + (size_t)b*65536 + d*256;
    float v[4];
#pragma unroll
    for (int i=0;i<4;++i) v[i] = fr[lane + i*64];
    float mx = fmaxf(fmaxf(v[0],v[1]), fmaxf(v[2],v[3]));
#pragma unroll
    for (int off=32; off>0; off>>=1) mx = fmaxf(mx, __shfl_xor(mx, off));
    float s = 0.f;
#pragma unroll
    for (int i=0;i<4;++i) { v[i] = __expf(v[i] - mx); s += v[i]; }
#pragma unroll
    for (int off=32; off>0; off>>=1) s += __shfl_xor(s, off);
    float inv = 1.f / s;
#pragma unroll
    for (int i=0;i<4;++i)
        F[(size_t)b*65536 + (size_t)(lane + i*64)*256 + d] = f2bf(v[i] * inv);
}

// ---------------- K2c: G[b][c][e] = sum_d F[c,d] g_w[d,e] ; yb = F@g_b
__global__ __launch_bounds__(256) void k2c(
    const short* __restrict__ F, const short* __restrict__ gwT,
    const float* __restrict__ g_b, short* __restrict__ G, float* __restrict__ yb)
{
    int bid = blockIdx.x;
    int b = bid >> 2, c0 = ((bid>>1)&1)*128, e0 = (bid&1)*128;
    int tid = threadIdx.x;
    int w = tid >> 6, lane = tid & 63;
    int wr = (w >> 1) * 64, wc = (w & 1) * 64;
    int quad = lane >> 4, l16 = lane & 15;

    f32x4 acc[4][4];
#pragma unroll
    for (int i=0;i<4;i++)
#pragma unroll
    for (int j=0;j<4;j++) acc[i][j] = f32x4{0.f,0.f,0.f,0.f};

    for (int s = 0; s < 8; ++s) {
        int k0 = s*32;
        s16x8 af[4], bfr[4];
#pragma unroll
        for (int mt=0; mt<4; ++mt)
            af[mt] = *(const s16x8*)(F + (size_t)b*65536 + (c0 + wr + mt*16 + l16)*256 + k0 + quad*8);
#pragma unroll
        for (int nt=0; nt<4; ++nt)
            bfr[nt] = *(const s16x8*)(gwT + (e0 + wc + nt*16 + l16)*256 + k0 + quad*8);
#pragma unroll
        for (int mt=0; mt<4; ++mt)
#pragma unroll
        for (int nt=0; nt<4; ++nt)
            acc[mt][nt] = MFMA16(af[mt], bfr[nt], acc[mt][nt]);
    }
#pragma unroll
    for (int mt=0; mt<4; ++mt)
#pragma unroll
    for (int nt=0; nt<4; ++nt)
#pragma unroll
    for (int r=0; r<4; ++r) {
        int c = c0 + wr + mt*16 + quad*4 + r;
        int e = e0 + wc + nt*16 + l16;
        G[(size_t)b*65536 + c*256 + e] = f2bf(acc[mt][nt][r]);
    }
    if (e0 == 0 && tid < 128) {
        int c = c0 + tid;
        float a = 0.f;
        const short* fr = F + (size_t)b*65536 + c*256;
        for (int d=0; d<256; ++d) a += bf2f(fr[d]) * g_b[d];
        yb[b*256 + c] = a;
    }
}

// ---------------- K3a: y = G @ x0 + yb, y2-flat [n][c] bf16.
// Swizzled dword LDS transpose of x0 + prefetch pipeline.
// grid = 8b * 256 m-blocks (m-block = 64 spatial positions)
__global__ __launch_bounds__(256) void k3a(
    const float* __restrict__ x0, const short* __restrict__ G,
    const float* __restrict__ yb, short* __restrict__ yv)
{
    __shared__ short smX[64*40];                 // rows n 64 x 40 shorts (20 dw)
    int bid = blockIdx.x;
    int b = bid >> 8, m0 = (bid & 255) * 64;
    int tid = threadIdx.x;
    int w = tid >> 6, lane = tid & 63;
    int quad = lane >> 4, l16 = lane & 15;
    int rc = w * 64;
    int se2 = tid >> 4;            // e-pair 0..15 (e-local = 2*se2, 2*se2+1)
    int g   = tid & 15;            // n-quad (n-local = 4g+j)
    int keyw = (g >> 1) & 3;       // = ((4g+j)>>3)&3 for j<4

    const float* px = x0 + (size_t)(b*256 + 2*se2)*16384 + m0 + 4*g;
    const short* Gb = G + (size_t)b*65536;
    uint32_t* smDW = (uint32_t*)smX;

    f32x4 acc[4][4];
#pragma unroll
    for (int i=0;i<4;i++)
#pragma unroll
    for (int j=0;j<4;j++) acc[i][j] = f32x4{0.f,0.f,0.f,0.f};

    // preload s=0
    f32x4 xr0 = *(const f32x4*)(px);
    f32x4 xr1 = *(const f32x4*)(px + 16384);
    px += (size_t)32*16384;
    s16x8 bfr[4];
#pragma unroll
    for (int nt=0; nt<4; ++nt)
        bfr[nt] = *(const s16x8*)(Gb + (rc + nt*16 + l16)*256 + quad*8);

    for (int s = 0; s < 8; ++s) {
        __syncthreads();
        float a0[4] = {xr0.x, xr0.y, xr0.z, xr0.w};
        float a1[4] = {xr1.x, xr1.y, xr1.z, xr1.w};
#pragma unroll
        for (int j=0;j<4;++j) {
            uint32_t u = cvtpk(a0[j], a1[j]);          // lo = even e
            smDW[(4*g + j)*20 + (se2 ^ (keyw << 2))] = u;
        }
        __syncthreads();
        f32x4 nx0, nx1; s16x8 nbf[4];
        if (s < 7) {
            nx0 = *(const f32x4*)(px);
            nx1 = *(const f32x4*)(px + 16384);
            px += (size_t)32*16384;
            int e0 = (s+1)*32;
#pragma unroll
            for (int nt=0; nt<4; ++nt)
                nbf[nt] = *(const s16x8*)(Gb + (rc + nt*16 + l16)*256 + e0 + quad*8);
        }
        s16x8 af[4];
#pragma unroll
        for (int mt=0; mt<4; ++mt) {
            int row = mt*16 + l16;
            int kk  = (row >> 3) & 3;
            af[mt] = *(const s16x8*)(smX + row*40 + 8*(quad ^ kk));
        }
#pragma unroll
        for (int mt=0; mt<4; ++mt)
#pragma unroll
        for (int nt=0; nt<4; ++nt)
            acc[mt][nt] = MFMA16(af[mt], bfr[nt], acc[mt][nt]);
        if (s < 7) {
            xr0 = nx0; xr1 = nx1;
#pragma unroll
            for (int nt=0; nt<4; ++nt) bfr[nt] = nbf[nt];
        }
    }
    float ybv[4];
#pragma unroll
    for (int nt=0; nt<4; ++nt) ybv[nt] = yb[b*256 + rc + nt*16 + l16];
    short* base = yv + (size_t)b*4194304 + (size_t)m0*256;
#pragma unroll
    for (int mt=0; mt<4; ++mt)
#pragma unroll
    for (int nt=0; nt<4; ++nt)
#pragma unroll
    for (int r=0; r<4; ++r) {
        int m  = mt*16 + quad*4 + r;
        int rr = rc + nt*16 + l16;
        base[m*256 + rr] = f2bf(acc[mt][nt][r] + ybv[nt]);
    }
}

// ---------------- K3b: out = W_w @ y_view + W_b. Swizzled dword LDS transpose
// of yv (view rows) + prefetch pipeline. grid = 8b * 2o * 128n
__global__ __launch_bounds__(256) void k3b(
    const short* __restrict__ yv, const short* __restrict__ Wwb,
    const float* __restrict__ W_b, float* __restrict__ out)
{
    __shared__ short smY[128*40];                // rows nv 128 x 40 shorts (20 dw)
    int bid = blockIdx.x;
    int b = bid >> 8, rem = bid & 255;
    int o0 = (rem >> 7) * 128, n0 = (rem & 127) * 128;
    int tid = threadIdx.x;
    int w = tid >> 6, lane = tid & 63;
    int wr = (w >> 1) * 64, wc = (w & 1) * 64;
    int quad = lane >> 4, l16 = lane & 15;
    int p   = tid >> 4;           // cv-pair 0..15 (cv-local = 2p, 2p+1)
    int nvg = tid & 15;           // nv-octet (nv-local = nvg*8+j)
    int keyw = nvg & 3;           // = ((nvg*8+j)>>3)&3 for j<8

    const short* py = yv + (size_t)b*4194304 + (size_t)(2*p)*16384 + n0 + nvg*8;
    uint32_t* smDW = (uint32_t*)smY;

    f32x4 acc[4][4];
#pragma unroll
    for (int i=0;i<4;i++)
#pragma unroll
    for (int j=0;j<4;j++) acc[i][j] = f32x4{0.f,0.f,0.f,0.f};

    // preload s=0
    s16x8 y0 = *(const s16x8*)(py);
    s16x8 y1 = *(const s16x8*)(py + 16384);
    py += (size_t)32*16384;
    s16x8 af[4];
#pragma unroll
    for (int mt=0; mt<4; ++mt)
        af[mt] = *(const s16x8*)(Wwb + (o0 + wr + mt*16 + l16)*256 + quad*8);

    for (int s = 0; s < 8; ++s) {
        __syncthreads();
#pragma unroll
        for (int j=0;j<8;++j) {
            uint32_t u = ((uint32_t)(uint16_t)y0[j]) | ((uint32_t)(uint16_t)y1[j] << 16);
            smDW[(nvg*8 + j)*20 + (p ^ (keyw << 2))] = u;
        }
        __syncthreads();
        s16x8 ny0, ny1, naf[4];
        if (s < 7) {
            ny0 = *(const s16x8*)(py);
            ny1 = *(const s16x8*)(py + 16384);
            py += (size_t)32*16384;
            int c0 = (s+1)*32;
#pragma unroll
            for (int mt=0; mt<4; ++mt)
                naf[mt] = *(const s16x8*)(Wwb + (o0 + wr + mt*16 + l16)*256 + c0 + quad*8);
        }
        s16x8 bfr[4];
#pragma unroll
        for (int nt=0; nt<4; ++nt) {
            int nv = wc + nt*16 + l16;
            int kk = (nv >> 3) & 3;
            bfr[nt] = *(const s16x8*)(smY + nv*40 + 8*(quad ^ kk));
        }
#pragma unroll
        for (int mt=0; mt<4; ++mt)
#pragma unroll
        for (int nt=0; nt<4; ++nt)
            acc[mt][nt] = MFMA16(af[mt], bfr[nt], acc[mt][nt]);
        if (s < 7) {
            y0 = ny0; y1 = ny1;
#pragma unroll
            for (int mt=0; mt<4; ++mt) af[mt] = naf[mt];
        }
    }
#pragma unroll
    for (int mt=0; mt<4; ++mt)
#pragma unroll
    for (int nt=0; nt<4; ++nt)
#pragma unroll
    for (int r=0; r<4; ++r) {
        int o  = o0 + wr + mt*16 + quad*4 + r;
        int nn = n0 + wc + nt*16 + l16;
        out[(size_t)(b*256 + o)*16384 + nn] = acc[mt][nt][r] + W_b[o];
    }
}

extern "C" void kernel_launch(void* const* d_in, const int* in_sizes, int n_in,
                              void* d_out, int out_size, void* d_ws, size_t ws_size,
                              hipStream_t stream)
{
    (void)in_sizes; (void)n_in; (void)out_size; (void)ws_size;
    const float* x0   = (const float*)d_in[0];
    const float* x1   = (const float*)d_in[1];
    const float* g_w  = (const float*)d_in[2];
    const float* g_b  = (const float*)d_in[3];
    const float* th_w = (const float*)d_in[4];
    const float* th_b = (const float*)d_in[5];
    const float* ph_w = (const float*)d_in[6];
    const float* ph_b = (const float*)d_in[7];
    const float* W_w  = (const float*)d_in[8];
    const float* W_b  = (const float*)d_in[9];
    float* out = (float*)d_out;

    char* ws = (char*)d_ws;
    short* yv      = (short*)(ws + 0);          // 67108864 B (aliases partial; dead->live handoff)
    float* partial = (float*)(ws + 0);          // 67108864 B (32 chunks), dead after k1_reduce
    float* M       = (float*)(ws + 67108864);   // 2 MB
    float* P1T     = (float*)(ws + 69206016);   // 2 MB
    float* fws     = (float*)(ws + 71303168);   // 2 MB
    short* F       = (short*)(ws + 73400320);   // 1 MB
    short* G       = (short*)(ws + 74448896);   // 1 MB
    short* gwT     = (short*)(ws + 75497472);   // 128 KB
    short* Wwb     = (short*)(ws + 75628544);   // 128 KB
    float* s0      = (float*)(ws + 75759616);
    float* s1      = (float*)(ws + 75767808);
    float* SA      = (float*)(ws + 75776000);
    float* SP      = (float*)(ws + 75784192);
    float* yb      = (float*)(ws + 75792384);

    k0_prep  <<<dim3(256),  dim3(256), 0, stream>>>(g_w, W_w, gwT, Wwb, s0, s1);
    k1_gram  <<<dim3(1024), dim3(256), 0, stream>>>(x0, x1, partial, s0, s1);
    k1_reduce<<<dim3(2048), dim3(256), 0, stream>>>(partial, M);
    k2m      <<<dim3(16),   dim3(256), 0, stream>>>(th_w, ph_w, ph_b, s0, s1, SA, SP);
    k2a      <<<dim3(32),   dim3(256), 0, stream>>>(ph_w, M, P1T);
    k2b1     <<<dim3(32),   dim3(256), 0, stream>>>(th_w, P1T, th_b, ph_b, SA, SP, fws);
    k2b2     <<<dim3(512),  dim3(256), 0, stream>>>(fws, F);
    k2c      <<<dim3(32),   dim3(256), 0, stream>>>(F, gwT, g_b, G, yb);
    k3a      <<<dim3(2048), dim3(256), 0, stream>>>(x0, G, yb, yv);
    k3b      <<<dim3(2048), dim3(256), 0, stream>>>(yv, Wwb, W_b, out);
}